// Round 8
// baseline (1250.349 us; speedup 1.0000x reference)
//
#include <hip/hip_runtime.h>

typedef __attribute__((ext_vector_type(8))) short short8;
typedef __attribute__((ext_vector_type(4))) float floatx4;

__device__ inline unsigned short f2bf(float f) {
  union { float f; unsigned u; } x; x.f = f;
  unsigned r = x.u + 0x7FFFu + ((x.u >> 16) & 1u);
  return (unsigned short)(r >> 16);
}
__device__ inline float bf2f(unsigned short h) {
  union { unsigned u; float f; } x; x.u = ((unsigned)h) << 16;
  return x.f;
}

#define GLL16(g, l)                                                  \
  __builtin_amdgcn_global_load_lds(                                  \
      (const __attribute__((address_space(1))) void*)(g),            \
      (__attribute__((address_space(3))) void*)(l), 16, 0, 0)

// ---------------- W -> bf16 chunked+swizzled layouts + zp + zero BN partials ----------------
__global__ __launch_bounds__(256) void convw_kernel(const float* __restrict__ W1,
                                                    const float* __restrict__ W2,
                                                    const float* __restrict__ Wup,
                                                    unsigned short* __restrict__ W1t,
                                                    unsigned short* __restrict__ W2t,
                                                    unsigned short* __restrict__ Wupt,
                                                    unsigned short* __restrict__ zp,
                                                    float* __restrict__ parts) {
  int idx = blockIdx.x * 256 + threadIdx.x;
  const int n1 = 27 * 96 * 64;
  const int n2 = 27 * 64 * 64;
  const int n3 = 8 * 32 * 96;
  if (idx < n1) {
    int k = idx / (96 * 64);
    int r = idx % (96 * 64);
    int q = r / 64, c = r % 64;
    int ch = q >> 3;
    int cs = c ^ ((ch & 3) << 1);
    W1t[(((size_t)k * 12 + ch) * 64 + cs) * 8 + (q & 7)] = f2bf(W1[idx]);
  } else if (idx < n1 + n2) {
    int j = idx - n1;
    int k = j / 4096;
    int r = j % 4096;
    int q = r / 64, c = r % 64;
    int ch = q >> 3;
    int cs = c ^ ((ch & 3) << 1);
    W2t[(((size_t)k * 8 + ch) * 64 + cs) * 8 + (q & 7)] = f2bf(W2[j]);
  } else if (idx < n1 + n2 + n3) {
    int o = idx - n1 - n2;
    int k = o / 3072;
    int r = o % 3072;
    int c = r / 96, q = r % 96;
    Wupt[o] = f2bf(Wup[((size_t)k * 96 + q) * 32 + c]);
  } else if (idx < n1 + n2 + n3 + 128) {
    zp[idx - n1 - n2 - n3] = 0;
  } else if (idx < n1 + n2 + n3 + 128 + 320) {
    parts[idx - n1 - n2 - n3 - 128] = 0.f;
  }
}

// ---------------- Upsample via masked 8-tap MFMA (atomic BN partials) ----------------
__global__ __launch_bounds__(256) void up_mfma_kernel(const float* __restrict__ x1,
                                                      const int* __restrict__ up_src,
                                                      const int* __restrict__ up_off,
                                                      const unsigned short* __restrict__ Wupt,
                                                      float* __restrict__ up_raw,
                                                      float* __restrict__ part1,
                                                      float* __restrict__ part2,
                                                      int N) {
  constexpr int PAD = 104;
  __shared__ unsigned short Wl[8 * 32 * PAD];
  __shared__ float wsum[4][32];
  __shared__ float wsq[4][32];

  const int tid = threadIdx.x;
  const int wv = tid >> 6;
  const int lane = tid & 63;
  const int lr = lane & 15;
  const int lg = lane >> 4;

  for (int ch = tid; ch < 8 * 32 * 12; ch += 256) {
    int kc = ch / 12, j = ch % 12;
    short8 v = *(const short8*)(Wupt + (size_t)kc * 96 + j * 8);
    *(short8*)(&Wl[kc * PAD + j * 8]) = v;
  }
  __syncthreads();

  const int nTiles = (N + 63) >> 6;
  const short8 z8 = {0, 0, 0, 0, 0, 0, 0, 0};
  float cs[2] = {0.f, 0.f}, cq[2] = {0.f, 0.f};

  for (int tile = blockIdx.x; tile < nTiles; tile += gridDim.x) {
    const int base = tile * 64;
    const int r = base + wv * 16 + lr;
    int o = -100;
    const float* ptr = x1;
    if (r < N) {
      o = up_off[r];
      ptr = x1 + (size_t)up_src[r] * 96;
    }
    short8 a_all[3];
    #pragma unroll
    for (int s = 0; s < 3; ++s) {
      float4 f0 = *(const float4*)(ptr + s * 32 + lg * 8);
      float4 f1 = *(const float4*)(ptr + s * 32 + lg * 8 + 4);
      unsigned short u[8];
      u[0] = f2bf(f0.x); u[1] = f2bf(f0.y); u[2] = f2bf(f0.z); u[3] = f2bf(f0.w);
      u[4] = f2bf(f1.x); u[5] = f2bf(f1.y); u[6] = f2bf(f1.z); u[7] = f2bf(f1.w);
      a_all[s] = *(short8*)u;
    }
    if (r >= N) {
      #pragma unroll
      for (int s = 0; s < 3; ++s) a_all[s] = z8;
    }

    floatx4 acc[2];
    acc[0] = (floatx4){0.f, 0.f, 0.f, 0.f};
    acc[1] = (floatx4){0.f, 0.f, 0.f, 0.f};
    #pragma unroll
    for (int k = 0; k < 8; ++k) {
      bool sel = (o == k);
      #pragma unroll
      for (int s = 0; s < 3; ++s) {
        short8 af = sel ? a_all[s] : z8;
        #pragma unroll
        for (int ct = 0; ct < 2; ++ct) {
          short8 bf = *(const short8*)(&Wl[(k * 32 + ct * 16 + lr) * PAD + s * 32 + lg * 8]);
          acc[ct] = __builtin_amdgcn_mfma_f32_16x16x32_bf16(af, bf, acc[ct], 0, 0, 0);
        }
      }
    }
    #pragma unroll
    for (int ct = 0; ct < 2; ++ct) {
      #pragma unroll
      for (int reg = 0; reg < 4; ++reg) {
        float v = acc[ct][reg];
        int r2 = base + wv * 16 + lg * 4 + reg;
        if (r2 < N) up_raw[(size_t)r2 * 32 + ct * 16 + lr] = v;
        cs[ct] += v;
        cq[ct] += v * v;
      }
    }
  }

  #pragma unroll
  for (int ct = 0; ct < 2; ++ct) {
    float a = cs[ct], b = cq[ct];
    a += __shfl_xor(a, 16);
    a += __shfl_xor(a, 32);
    b += __shfl_xor(b, 16);
    b += __shfl_xor(b, 32);
    if (lg == 0) {
      wsum[wv][ct * 16 + lr] = a;
      wsq[wv][ct * 16 + lr] = b;
    }
  }
  __syncthreads();
  if (tid < 32) {
    float s1 = wsum[0][tid] + wsum[1][tid] + wsum[2][tid] + wsum[3][tid];
    float s2 = wsq[0][tid] + wsq[1][tid] + wsq[2][tid] + wsq[3][tid];
    atomicAdd(&part1[tid], s1);
    atomicAdd(&part2[tid], s2);
  }
}

// ---------------- Concat (folds BN-up finalize) ----------------
__global__ __launch_bounds__(256) void concat_kernel(const float* __restrict__ up_raw,
                                                     const float* __restrict__ x2,
                                                     const float* __restrict__ x3,
                                                     const float* __restrict__ part1,
                                                     const float* __restrict__ part2,
                                                     const float* __restrict__ g,
                                                     const float* __restrict__ b,
                                                     unsigned short* __restrict__ xb,
                                                     int N) {
  __shared__ float ssb[64];
  if (threadIdx.x < 32) {
    int c = threadIdx.x;
    float mean = part1[c] / (float)N;
    float var = part2[c] / (float)N - mean * mean;
    float sc = g[c] * rsqrtf(var + 1e-5f);
    ssb[c] = sc;
    ssb[32 + c] = b[c] - mean * sc;
  }
  __syncthreads();
  int total = N * 12;
  for (int idx = blockIdx.x * 256 + threadIdx.x; idx < total; idx += gridDim.x * 256) {
    int row = idx / 12, p = idx % 12;
    float v[8];
    if (p < 4) {
      const float* s = up_raw + (size_t)row * 32 + p * 8;
      int c0 = p * 8;
      #pragma unroll
      for (int j = 0; j < 8; ++j) v[j] = fmaxf(s[j] * ssb[c0 + j] + ssb[32 + c0 + j], 0.f);
    } else if (p < 8) {
      const float* s = x2 + (size_t)row * 32 + (p - 4) * 8;
      #pragma unroll
      for (int j = 0; j < 8; ++j) v[j] = s[j];
    } else {
      const float* s = x3 + (size_t)row * 32 + (p - 8) * 8;
      #pragma unroll
      for (int j = 0; j < 8; ++j) v[j] = s[j];
    }
    unsigned short o[8];
    #pragma unroll
    for (int j = 0; j < 8; ++j) o[j] = f2bf(v[j]);
    ((uint4*)xb)[idx] = *(uint4*)o;
  }
}

// ---------------- SubM conv: group-staged LDS B, in-register A pipeline ----------------
// Block = 512 thr (8 waves) = 4 row-groups x 2 col-groups; wave = 32 rows x 32 cols.
// 9 groups x 3 taps; double-buffered LDS B; one barrier per group.

#define CONV_GATH(Ab, F0, F1, I0, I1)                                          \
  {                                                                            \
    F0 = __any((I0) >= 0);                                                     \
    F1 = __any((I1) >= 0);                                                     \
    const unsigned short* _s0 = ((I0) >= 0) ? feats + (size_t)(I0) * CIN : zp; \
    const unsigned short* _s1 = ((I1) >= 0) ? feats + (size_t)(I1) * CIN : zp; \
    if (F0) {                                                                  \
      _Pragma("unroll")                                                        \
      for (int s = 0; s < KS; ++s) Ab[s] = *(const short8*)(_s0 + s * 32 + lg * 8); \
    }                                                                          \
    if (F1) {                                                                  \
      _Pragma("unroll")                                                        \
      for (int s = 0; s < KS; ++s) Ab[KS + s] = *(const short8*)(_s1 + s * 32 + lg * 8); \
    }                                                                          \
  }

#define CONV_STEP(T, TL, P, Ab, F0, F1)                                        \
  {                                                                            \
    if (F0 | F1) {                                                             \
      short8 Bf[2][KS];                                                        \
      _Pragma("unroll")                                                        \
      for (int s = 0; s < KS; ++s) {                                           \
        const int _u0 = (((P) * 3 + (TL)) * CH + s * 4 + lg) * 64;             \
        Bf[0][s] = *(const short8*)(&Bl[(size_t)(_u0 + ((wcol * 32 + 0 * 16 + lr) ^ (lg << 1))) * 8]); \
        Bf[1][s] = *(const short8*)(&Bl[(size_t)(_u0 + ((wcol * 32 + 1 * 16 + lr) ^ (lg << 1))) * 8]); \
      }                                                                        \
      if (F0) {                                                                \
        _Pragma("unroll")                                                      \
        for (int s = 0; s < KS; ++s) {                                         \
          acc[0][0] = __builtin_amdgcn_mfma_f32_16x16x32_bf16(Ab[s], Bf[0][s], acc[0][0], 0, 0, 0); \
          acc[0][1] = __builtin_amdgcn_mfma_f32_16x16x32_bf16(Ab[s], Bf[1][s], acc[0][1], 0, 0, 0); \
        }                                                                      \
      }                                                                        \
      if (F1) {                                                                \
        _Pragma("unroll")                                                      \
        for (int s = 0; s < KS; ++s) {                                         \
          acc[1][0] = __builtin_amdgcn_mfma_f32_16x16x32_bf16(Ab[KS + s], Bf[0][s], acc[1][0], 0, 0, 0); \
          acc[1][1] = __builtin_amdgcn_mfma_f32_16x16x32_bf16(Ab[KS + s], Bf[1][s], acc[1][1], 0, 0, 0); \
        }                                                                      \
      }                                                                        \
    }                                                                          \
    if ((T) + 2 < 27) {                                                        \
      CONV_GATH(Ab, F0, F1, iA0, iA1)                                          \
    } else {                                                                   \
      F0 = false;                                                              \
      F1 = false;                                                              \
    }                                                                          \
    iA0 = iB0; iA1 = iB1;                                                      \
    iB0 = ((T) + 4 < 27 && inb0) ? nrow0[(T) + 4] : -1;                        \
    iB1 = ((T) + 4 < 27 && inb1) ? nrow1[(T) + 4] : -1;                        \
  }

#define STAGEG(G, P)                                                           \
  {                                                                            \
    const unsigned short* _src = Wt + (size_t)(G) * UNITS * 8;                 \
    _Pragma("unroll")                                                          \
    for (int i = 0; i < NSTG; ++i) {                                           \
      int _wb = i * 512 + wv * 64;                                             \
      if (_wb < UNITS)                                                         \
        GLL16(_src + (size_t)(_wb + lane) * 8,                                 \
              &Bl[((size_t)(P) * UNITS + _wb) * 8]);                           \
    }                                                                          \
  }

template <int CIN, bool OUTBF>
__global__ __launch_bounds__(512, 4) void conv_kernel(const unsigned short* __restrict__ feats,
                                                      const unsigned short* __restrict__ Wt,
                                                      const int* __restrict__ nbr,
                                                      const unsigned short* __restrict__ zp,
                                                      void* __restrict__ yout,
                                                      float* __restrict__ part1,
                                                      float* __restrict__ part2,
                                                      int N) {
  constexpr int KS = CIN / 32;
  constexpr int CH = CIN / 8;
  constexpr int UNITS = 3 * CH * 64;
  constexpr int NSTG = (UNITS + 511) / 512;
  __shared__ unsigned short Bl[2 * UNITS * 8];
  __shared__ float wsum[8][32];
  __shared__ float wsq[8][32];

  const int tid = threadIdx.x;
  const int wv = tid >> 6;
  const int lane = tid & 63;
  const int lr = lane & 15;
  const int lg = lane >> 4;
  const int wrow = wv >> 1;   // 0..3
  const int wcol = wv & 1;    // 0..1
  const int tbase = blockIdx.x * 128;
  const int r0 = tbase + wrow * 32 + lr;
  const int r1 = r0 + 16;
  const bool inb0 = (r0 < N);
  const bool inb1 = (r1 < N);
  const int* nrow0 = nbr + (size_t)r0 * 27;
  const int* nrow1 = nbr + (size_t)r1 * 27;

  floatx4 acc[2][2];
  #pragma unroll
  for (int m = 0; m < 2; ++m)
    #pragma unroll
    for (int ct = 0; ct < 2; ++ct) acc[m][ct] = (floatx4){0.f, 0.f, 0.f, 0.f};

  short8 A0[2 * KS], A1[2 * KS];
  bool aF0, aF1, bF0, bF1;
  int iA0, iA1, iB0, iB1;

  {
    int j00 = inb0 ? nrow0[0] : -1;
    int j01 = inb1 ? nrow1[0] : -1;
    CONV_GATH(A0, aF0, aF1, j00, j01)
    int j10 = inb0 ? nrow0[1] : -1;
    int j11 = inb1 ? nrow1[1] : -1;
    CONV_GATH(A1, bF0, bF1, j10, j11)
  }
  iA0 = inb0 ? nrow0[2] : -1;
  iA1 = inb1 ? nrow1[2] : -1;
  iB0 = inb0 ? nrow0[3] : -1;
  iB1 = inb1 ? nrow1[3] : -1;
  STAGEG(0, 0)
  __syncthreads();

  #pragma unroll 1
  for (int g = 0; g < 9; ++g) {
    if (g < 8) STAGEG(g + 1, (g + 1) & 1)
    const int tb = g * 3;
    if ((g & 1) == 0) {
      CONV_STEP(tb + 0, 0, 0, A0, aF0, aF1)
      CONV_STEP(tb + 1, 1, 0, A1, bF0, bF1)
      CONV_STEP(tb + 2, 2, 0, A0, aF0, aF1)
    } else {
      CONV_STEP(tb + 0, 0, 1, A1, bF0, bF1)
      CONV_STEP(tb + 1, 1, 1, A0, aF0, aF1)
      CONV_STEP(tb + 2, 2, 1, A1, bF0, bF1)
    }
    if (g < 8) __syncthreads();
  }

  // epilogue: store + BN partials
  float cs[2] = {0.f, 0.f}, cq[2] = {0.f, 0.f};
  #pragma unroll
  for (int m = 0; m < 2; ++m) {
    #pragma unroll
    for (int ct = 0; ct < 2; ++ct) {
      #pragma unroll
      for (int reg = 0; reg < 4; ++reg) {
        float v = acc[m][ct][reg];
        int r2 = tbase + wrow * 32 + m * 16 + lg * 4 + reg;
        int col = wcol * 32 + ct * 16 + lr;
        if (r2 < N) {
          if (OUTBF)
            ((unsigned short*)yout)[(size_t)r2 * 64 + col] = f2bf(v);
          else
            ((float*)yout)[(size_t)r2 * 64 + col] = v;
        }
        cs[ct] += v;
        cq[ct] += v * v;
      }
    }
  }
  #pragma unroll
  for (int ct = 0; ct < 2; ++ct) {
    float a = cs[ct], b = cq[ct];
    a += __shfl_xor(a, 16);
    a += __shfl_xor(a, 32);
    b += __shfl_xor(b, 16);
    b += __shfl_xor(b, 32);
    if (lg == 0) {
      wsum[wv][ct * 16 + lr] = a;
      wsq[wv][ct * 16 + lr] = b;
    }
  }
  __syncthreads();
  // wsum[wv][c32]: wave wv covered cols wcol*32 + c32. Reduce per output col (64).
  if (tid < 64) {
    int wc = tid >> 5;       // which 32-col half
    int c32 = tid & 31;
    float s1 = 0.f, s2 = 0.f;
    #pragma unroll
    for (int wr2 = 0; wr2 < 4; ++wr2) {
      s1 += wsum[wr2 * 2 + wc][c32];
      s2 += wsq[wr2 * 2 + wc][c32];
    }
    atomicAdd(&part1[tid], s1);
    atomicAdd(&part2[tid], s2);
  }
}

#undef CONV_STEP
#undef CONV_GATH
#undef STAGEG

// ---------------- Apply BN+ReLU in place on bf16 (folds bn1 finalize) ----------------
__global__ __launch_bounds__(256) void apply_bn_bf16_inplace(unsigned short* __restrict__ y,
                                                             const float* __restrict__ part1,
                                                             const float* __restrict__ part2,
                                                             const float* __restrict__ g,
                                                             const float* __restrict__ b,
                                                             int N) {
  __shared__ float ssb[128];
  if (threadIdx.x < 64) {
    int c = threadIdx.x;
    float mean = part1[c] / (float)N;
    float var = part2[c] / (float)N - mean * mean;
    float sc = g[c] * rsqrtf(var + 1e-5f);
    ssb[c] = sc;
    ssb[64 + c] = b[c] - mean * sc;
  }
  __syncthreads();
  int total = N * 8;
  for (int idx = blockIdx.x * 256 + threadIdx.x; idx < total; idx += gridDim.x * 256) {
    int c0 = (idx & 7) * 8;
    uint4 d = ((uint4*)y)[idx];
    unsigned short* u = (unsigned short*)&d;
    #pragma unroll
    for (int j = 0; j < 8; ++j) {
      float f = bf2f(u[j]);
      f = fmaxf(f * ssb[c0 + j] + ssb[64 + c0 + j], 0.f);
      u[j] = f2bf(f);
    }
    ((uint4*)y)[idx] = d;
  }
}

// ---------------- Apply BN+ReLU in place, fp32 (folds bn2 finalize) ----------------
__global__ __launch_bounds__(256) void apply_bn_inplace(float* __restrict__ y,
                                                        const float* __restrict__ part1,
                                                        const float* __restrict__ part2,
                                                        const float* __restrict__ g,
                                                        const float* __restrict__ b,
                                                        int N) {
  __shared__ float ssb[128];
  if (threadIdx.x < 64) {
    int c = threadIdx.x;
    float mean = part1[c] / (float)N;
    float var = part2[c] / (float)N - mean * mean;
    float sc = g[c] * rsqrtf(var + 1e-5f);
    ssb[c] = sc;
    ssb[64 + c] = b[c] - mean * sc;
  }
  __syncthreads();
  int total = N * 16;
  for (int idx = blockIdx.x * 256 + threadIdx.x; idx < total; idx += gridDim.x * 256) {
    int c0 = (idx & 15) * 4;
    float4 d = ((float4*)y)[idx];
    d.x = fmaxf(d.x * ssb[c0 + 0] + ssb[64 + c0 + 0], 0.f);
    d.y = fmaxf(d.y * ssb[c0 + 1] + ssb[64 + c0 + 1], 0.f);
    d.z = fmaxf(d.z * ssb[c0 + 2] + ssb[64 + c0 + 2], 0.f);
    d.w = fmaxf(d.w * ssb[c0 + 3] + ssb[64 + c0 + 3], 0.f);
    ((float4*)y)[idx] = d;
  }
}

extern "C" void kernel_launch(void* const* d_in, const int* in_sizes, int n_in,
                              void* d_out, int out_size, void* d_ws, size_t ws_size,
                              hipStream_t stream) {
  const float* x1 = (const float*)d_in[0];
  const float* x2 = (const float*)d_in[1];
  const float* x3 = (const float*)d_in[2];
  const float* Wup = (const float*)d_in[3];
  const float* gup = (const float*)d_in[4];
  const float* bup = (const float*)d_in[5];
  const float* W1 = (const float*)d_in[6];
  const float* g1 = (const float*)d_in[7];
  const float* b1 = (const float*)d_in[8];
  const float* W2 = (const float*)d_in[9];
  const float* g2 = (const float*)d_in[10];
  const float* b2 = (const float*)d_in[11];
  const int* up_src = (const int*)d_in[12];
  const int* up_off = (const int*)d_in[13];
  const int* nbr = (const int*)d_in[14];

  const int N = in_sizes[12];
  const int NT = (N + 127) / 128;

  char* ws = (char*)d_ws;
  size_t off = 0;
  auto alloc = [&](size_t bytes) -> void* {
    void* p = ws + off;
    off = (off + bytes + 255) & ~(size_t)255;
    return p;
  };

  unsigned short* xb   = (unsigned short*)alloc((size_t)N * 96 * 2);
  unsigned short* y1b  = (unsigned short*)alloc((size_t)N * 64 * 2);
  float* up_raw        = (float*)alloc((size_t)N * 32 * 4);
  unsigned short* W1t  = (unsigned short*)alloc((size_t)27 * 64 * 96 * 2);
  unsigned short* W2t  = (unsigned short*)alloc((size_t)27 * 64 * 64 * 2);
  unsigned short* Wupt = (unsigned short*)alloc((size_t)8 * 32 * 96 * 2);
  unsigned short* zp   = (unsigned short*)alloc(256);
  float* parts         = (float*)alloc(320 * 4);
  (void)ws_size;

  float* upP1 = parts;
  float* upP2 = parts + 32;
  float* c1P1 = parts + 64;
  float* c1P2 = parts + 128;
  float* c2P1 = parts + 192;
  float* c2P2 = parts + 256;

  float* out = (float*)d_out;

  convw_kernel<<<1179, 256, 0, stream>>>(W1, W2, Wup, W1t, W2t, Wupt, zp, parts);
  up_mfma_kernel<<<1024, 256, 0, stream>>>(x1, up_src, up_off, Wupt, up_raw, upP1, upP2, N);
  concat_kernel<<<2048, 256, 0, stream>>>(up_raw, x2, x3, upP1, upP2, gup, bup, xb, N);
  conv_kernel<96, true><<<NT, 512, 0, stream>>>(xb, W1t, nbr, zp, y1b, c1P1, c1P2, N);
  apply_bn_bf16_inplace<<<2048, 256, 0, stream>>>(y1b, c1P1, c1P2, g1, b1, N);
  conv_kernel<64, false><<<NT, 512, 0, stream>>>(y1b, W2t, nbr, zp, out, c2P1, c2P2, N);
  apply_bn_inplace<<<2048, 256, 0, stream>>>(out, c2P1, c2P2, g2, b2, N);
}